// Round 18
// baseline (96.976 us; speedup 1.0000x reference)
//
#include <hip/hip_runtime.h>
#include <stdint.h>

#define BB 4
#define NN 32768
#define PRE 4096
#define POST 512
#define NMS_TH 0.7f
#define MIDCAP 8192
#define NWAVE 16
#define KCAP 576          // max kept before early-exit: 511 + 64

typedef unsigned long long u64;
typedef unsigned int u32;

__device__ __forceinline__ u32 orderable(float f) {
  u32 u = __float_as_uint(f);
  return (u & 0x80000000u) ? ~u : (u | 0x80000000u);
}
__device__ __forceinline__ float unorderable(u32 o) {
  u32 u = (o & 0x80000000u) ? (o & 0x7fffffffu) : ~o;
  return __uint_as_float(u);
}
// Monotone fixed-point bucket: uniform in score space (scores in [0,1)).
__device__ __forceinline__ u32 bucket_of(float s) {
  u32 v = (u32)(s * 2147483648.0f);
  u32 bk = v >> 20;
  return bk > 2047u ? 2047u : bk;
}
__device__ __forceinline__ u64 readlane64(u64 v, int l) {
  u32 lo = (u32)__builtin_amdgcn_readlane((int)(u32)v, l);
  u32 hi = (u32)__builtin_amdgcn_readlane((int)(u32)(v >> 32), l);
  return ((u64)hi << 32) | lo;
}
// IoU fast compare (threshold form) with margin tracking; exact-divide twin.
// Same op order as reference: denom = ((a1 + a2) - inter) + 1e-6.
__device__ __forceinline__ bool iou_fast(float4 a, float aa, float4 b, float ba, float& mm) {
  float ix = fminf(a.z, b.z) - fmaxf(a.x, b.x); ix = fmaxf(0.0f, ix);
  float iy = fminf(a.w, b.w) - fmaxf(a.y, b.y); iy = fmaxf(0.0f, iy);
  float inter = ix * iy;
  float denom = ((aa + ba) - inter) + 1e-6f;
  float t = 0.7f * denom;
  mm = fminf(mm, fabsf(inter - t) - 2e-5f * t);   // band >> max rounding skew (~4e-7)
  return inter > t;
}
__device__ __forceinline__ bool iou_exact(float4 a, float aa, float4 b, float ba) {
  float ix = fminf(a.z, b.z) - fmaxf(a.x, b.x); ix = fmaxf(0.0f, ix);
  float iy = fminf(a.w, b.w) - fmaxf(a.y, b.y); iy = fmaxf(0.0f, iy);
  float inter = ix * iy;
  float denom = ((aa + ba) - inter) + 1e-6f;
  return (inter / denom) > NMS_TH;
}

// ONE block per batch (1024 threads = 16 waves); the whole pipeline runs with
// __syncthreads hand-offs — zero cross-block communication, one launch total.
// The mask matrix is never materialized: candidates are checked directly
// against the kept list (kn <= 575 before early-exit -> kept P/AR fit in LDS).
__global__ __launch_bounds__(1024, 1) void nms_all_kernel(
    const float* __restrict__ boxes, const float* __restrict__ cls,
    u64* __restrict__ keysG, int* __restrict__ labelsG,
    u64* __restrict__ selG, u64* __restrict__ midG,
    float4* __restrict__ Pg, float* __restrict__ ARg,
    float* __restrict__ topBox, float* __restrict__ topS, int* __restrict__ topL,
    float* __restrict__ out) {
  __shared__ u32 sfx[2048];        // hist -> suffix sums (persist)
  __shared__ u32 cursor[2048];     // per-bucket write cursors
  __shared__ float4 keptP[KCAP];
  __shared__ float keptAR[KCAP];
  __shared__ u64 dLDS[64];
  __shared__ u64 kwLDS[64];
  __shared__ u32 supArr[64];
  __shared__ u32 midCnt, Tsh, C1sh, knSh;

  int b = blockIdx.x;
  int tid = threadIdx.x;
  int wv = tid >> 6, lane = tid & 63;

  if (tid == 0) { midCnt = 0; knSh = 0; }
  if (tid < 64) kwLDS[tid] = 0;
  for (int t = tid; t < 2048; t += 1024) sfx[t] = 0;
  __syncthreads();

  // ---- A: scores / keys / labels / LDS histogram (4 pts per iter, x8) ----
  u64* keysB = keysG + (size_t)b * NN;
  int* labsB = labelsG + (size_t)b * NN;
  const float* clsB = cls + (size_t)b * NN * 3;
  for (int c = 0; c < 8; ++c) {
    int t4 = tid + c * 1024;                       // [0, 8192)
    const float4* c4 = (const float4*)(clsB + (size_t)t4 * 12);
    float4 va = c4[0], vb = c4[1], vc = c4[2];
    float v[12] = {va.x, va.y, va.z, va.w, vb.x, vb.y, vb.z, vb.w, vc.x, vc.y, vc.z, vc.w};
    u64 ks[4]; int ls[4];
#pragma unroll
    for (int p = 0; p < 4; ++p) {
      float s = v[3 * p]; int l = 0;
      if (v[3 * p + 1] > s) { s = v[3 * p + 1]; l = 1; }
      if (v[3 * p + 2] > s) { s = v[3 * p + 2]; l = 2; }
      int n = t4 * 4 + p;
      ks[p] = ((u64)orderable(s) << 32) | (u32)(~(u32)n);
      ls[p] = l;
      atomicAdd(&sfx[bucket_of(s)], 1u);
    }
    *(ulonglong2*)(keysB + t4 * 4) = make_ulonglong2(ks[0], ks[1]);
    *(ulonglong2*)(keysB + t4 * 4 + 2) = make_ulonglong2(ks[2], ks[3]);
    *(int4*)(labsB + t4 * 4) = make_int4(ls[0], ls[1], ls[2], ls[3]);
  }
  __syncthreads();

  // ---- select: suffix-scan sfx (2 elems/thread); find T; init cursors ----
  for (int d = 1; d < 2048; d <<= 1) {
    int t0 = tid, t1 = tid + 1024;
    u32 v0 = (t0 + d < 2048) ? sfx[t0 + d] : 0;
    u32 v1 = (t1 + d < 2048) ? sfx[t1 + d] : 0;
    __syncthreads();
    sfx[t0] += v0; sfx[t1] += v1;
    __syncthreads();
  }
#pragma unroll
  for (int i = 0; i < 2; ++i) {
    int t = tid + i * 1024;
    u32 above = (t + 1 < 2048) ? sfx[t + 1] : 0;
    cursor[t] = above;                             // segment base
    if (above < PRE && sfx[t] >= PRE) { Tsh = (u32)t; C1sh = above; }
  }
  __syncthreads();
  u32 T = Tsh, C1 = C1sh;

  // ---- B: compact via LDS cursors ----
  u64* selB = selG + ((size_t)b << 12);
  u64* midB = midG + (size_t)b * MIDCAP;
  for (int c = 0; c < 8; ++c) {
    int t4 = tid + c * 1024;
    ulonglong2 k01 = *(const ulonglong2*)(keysB + t4 * 4);
    ulonglong2 k23 = *(const ulonglong2*)(keysB + t4 * 4 + 2);
    u64 kk[4] = {k01.x, k01.y, k23.x, k23.y};
#pragma unroll
    for (int p = 0; p < 4; ++p) {
      u64 key = kk[p];
      u32 bk = bucket_of(unorderable((u32)(key >> 32)));
      if (bk > T) {
        u32 q = atomicAdd(&cursor[bk], 1u);
        selB[q] = key;
      } else if (bk == T) {
        u32 q = atomicAdd(&midCnt, 1u);
        if (q < MIDCAP) midB[q] = key;             // ~45 expected with this data
      }
    }
  }
  __syncthreads();

  // ---- C: per-wave bucket sort (t > T) + midsel (t == T, wave 0) ----
  for (int t = (int)T + wv; t < 2048; t += NWAVE) {
    if (t == (int)T) {
      int need = PRE - (int)C1;
      int M = (int)midCnt; if (M > MIDCAP) M = MIDCAP;
      for (int r = 0; r < need; ++r) {
        u64 best = 0; int bi = -1;
        for (int q = lane; q < M; q += 64) {
          u64 v = midB[q];
          if (v > best) { best = v; bi = q; }
        }
#pragma unroll
        for (int d = 32; d > 0; d >>= 1) {
          u64 ob = __shfl_xor(best, d, 64);
          int oi = __shfl_xor(bi, d, 64);
          if (ob > best) { best = ob; bi = oi; }
        }
        if (lane == 0) selB[C1 + r] = best;
        if (bi >= 0 && lane == (bi & 63)) midB[bi] = 0;  // remove chosen
      }
      continue;
    }
    u32 start = (t < 2047) ? sfx[t + 1] : 0u;
    u32 end = sfx[t];
    int n = (int)(end - start);
    if (n <= 1) continue;
    if (n <= 64) {
      u64 v = (lane < n) ? selB[start + lane] : 0ULL;    // MSB-set keys: pad sinks
#pragma unroll
      for (int k = 2; k <= 64; k <<= 1) {
#pragma unroll
        for (int j = k >> 1; j > 0; j >>= 1) {
          u64 o = __shfl_xor(v, j, 64);
          bool up = ((lane & k) == 0);
          bool first = ((lane & j) == 0);
          u64 mx = v > o ? v : o, mn = v > o ? o : v;
          v = (first == up) ? mx : mn;
        }
      }
      if (lane < n) selB[start + lane] = v;
    } else {
      // robustness fallback (never hit on bench data): selection sort
      for (int r = 0; r < n - 1; ++r) {
        u64 best = 0; int bi = -1;
        for (int q = r + lane; q < n; q += 64) {
          u64 v = selB[start + q];
          if (v > best) { best = v; bi = q; }
        }
#pragma unroll
        for (int d = 32; d > 0; d >>= 1) {
          u64 ob = __shfl_xor(best, d, 64);
          int oi = __shfl_xor(bi, d, 64);
          if (ob > best) { best = ob; bi = oi; }
        }
        if (lane == 0) {
          u64 tmp = selB[start + r];
          selB[start + r] = best;
          selB[start + bi] = tmp;
        }
      }
    }
  }
  __syncthreads();

  // ---- D: gather box data for the sorted top-4096 ----
  for (int c = 0; c < 4; ++c) {
    int pos = tid + c * 1024;
    u64 key = selB[pos];
    u32 n = ~(u32)key;
    size_t src = (size_t)b * NN + n;
    const float* bx = boxes + src * 7;
    float x = bx[0], y = bx[1], dx = bx[3], dy = bx[4];
    size_t gidx = ((size_t)b << 12) + pos;
    float* tb = topBox + gidx * 7;
#pragma unroll
    for (int cc = 0; cc < 7; ++cc) tb[cc] = bx[cc];
    float4 p;
    p.x = x - 0.5f * dx; p.z = x + 0.5f * dx;      // 0.5*dx exact -> contraction-safe
    p.y = y - 0.5f * dy; p.w = y + 0.5f * dy;
    Pg[gidx] = p;
    ARg[gidx] = dx * dy;
    topS[gidx] = unorderable((u32)(key >> 32));
    topL[gidx] = labelsG[src];
  }
  __syncthreads();

  // ---- E: greedy NMS, group-of-64, directly vs the kept list ----
  size_t pb = (size_t)b << 12;
  for (int g = 0; g < 64; ++g) {
    int kn0 = (int)knSh;                           // stable since last barrier
    // 1. sup pass: wave wv owns candidates 4wv..4wv+3; 16 lanes split kept list
    int cj = g * 64 + 4 * wv + (lane >> 4);
    float4 cp = Pg[pb + cj];
    float car = ARg[pb + cj];
    bool hit = false; float mm = 1.0f;
    for (int m = (lane & 15); m < kn0; m += 16) {
      hit |= iou_fast(keptP[m], keptAR[m], cp, car, mm);
    }
    if (__any(mm <= 0.0f)) {                       // rare: exact-divide redo
      hit = false;
      for (int m = (lane & 15); m < kn0; m += 16)
        hit |= iou_exact(keptP[m], keptAR[m], cp, car);
    }
    u64 bal = __ballot(hit);
    int q = lane >> 4;
    if ((lane & 15) == 0)
      supArr[4 * wv + q] = (((bal >> (16 * q)) & 0xFFFFull) != 0ull) ? 1u : 0u;
    // 2. intra-group tile: wave wv computes rows 4wv..4wv+3 (lane = column)
    float4 cq = Pg[pb + g * 64 + lane];
    float cqa = ARg[pb + g * 64 + lane];
#pragma unroll
    for (int rr = 0; rr < 4; ++rr) {
      int rj = g * 64 + 4 * wv + rr;
      float4 rp = Pg[pb + rj];
      float rar = ARg[pb + rj];
      float mm2 = 1.0f;
      bool sup = iou_fast(rp, rar, cq, cqa, mm2);
      if (__any(mm2 <= 0.0f)) sup = iou_exact(rp, rar, cq, cqa);
      u64 dw = __ballot(sup);
      if (lane == 0) dLDS[4 * wv + rr] = dw;
    }
    __syncthreads();
    // 3. wave 0: sparse intra-group recurrence (verbatim R14 core) + append
    if (wv == 0) {
      u64 d_cur = dLDS[lane];
      u64 sup_word = __ballot(supArr[lane] != 0u);
      u64 aboveMask = ~((2ULL << lane) - 1ULL);    // lane=63 -> 0
      u64 rem = __ballot((d_cur & aboveMask) != 0ULL);
      if (rem) {                                   // rare: real intra suppressors
        do {
          int k = __ffsll((long long)rem) - 1;
          rem &= rem - 1;
          if (!((sup_word >> k) & 1ULL))           // row k kept -> apply bits >k
            sup_word |= readlane64(d_cur, k) & ~((2ULL << k) - 1ULL);
        } while (rem);
      }
      u64 keep = ~sup_word;
      int cnt = __popcll(keep);
      int rank = (int)__popcll(keep & ((1ULL << lane) - 1ULL));
      if ((keep >> lane) & 1ULL) {                 // kn0+rank <= 574 < KCAP
        int bi = g * 64 + lane;
        keptP[kn0 + rank] = Pg[pb + bi];
        keptAR[kn0 + rank] = ARg[pb + bi];
      }
      if (lane == 0) { kwLDS[g] = keep; knSh = (u32)(kn0 + cnt); }
    }
    __syncthreads();
    if (knSh >= POST) break;                       // uniform
  }

  // ---- finalize (wave 0): expand keep words, write output ----
  if (wv != 0) return;
  u64 kw = kwLDS[lane];
  int cnt = __popcll(kw);
  int pfx = cnt;
#pragma unroll
  for (int d = 1; d < 64; d <<= 1) {
    int up = __shfl_up(pfx, d, 64);
    if (lane >= d) pfx += up;
  }
  int total = __shfl(pfx, 63, 64);
  int pos = pfx - cnt;
  float* outR = out;
  float* outS = out + BB * POST * 7;
  float* outL = outS + BB * POST;
  while (kw) {
    int t = __ffsll((long long)kw) - 1;
    kw &= kw - 1;
    if (pos < POST) {
      int i = (lane << 6) + t;
      int gdx = (b << 9) + pos;
      const float* tb = topBox + (pb + i) * 7;
#pragma unroll
      for (int c = 0; c < 7; ++c) outR[(size_t)gdx * 7 + c] = tb[c];
      outS[gdx] = topS[pb + i];
      outL[gdx] = (float)(topL[pb + i] + 1);
    }
    ++pos;
  }
  int fin = total < POST ? total : POST;
  for (int s = fin + lane; s < POST; s += 64) {    // empty slots: 0 / 0 / label 1
    int gdx = (b << 9) + s;
#pragma unroll
    for (int c = 0; c < 7; ++c) outR[(size_t)gdx * 7 + c] = 0.0f;
    outS[gdx] = 0.0f;
    outL[gdx] = 1.0f;
  }
}

extern "C" void kernel_launch(void* const* d_in, const int* in_sizes, int n_in,
                              void* d_out, int out_size, void* d_ws, size_t ws_size,
                              hipStream_t stream) {
  const float* boxes = (const float*)d_in[0];   // (4,32768,7)
  const float* cls   = (const float*)d_in[1];   // (4,32768,3)
  float* out = (float*)d_out;

  // ---- workspace carve-up (~3 MB) ----
  char* p = (char*)d_ws;
  auto take = [&](size_t bytes) { char* r = p; p += (bytes + 255) & ~(size_t)255; return (void*)r; };
  u64*   keys    = (u64*)  take((size_t)BB * NN * 8);
  int*   labels  = (int*)  take((size_t)BB * NN * 4);
  u64*   sel     = (u64*)  take((size_t)BB * PRE * 8);
  u64*   mid     = (u64*)  take((size_t)BB * MIDCAP * 8);
  float4* Pg     = (float4*)take((size_t)BB * PRE * 16);
  float* ARg     = (float*)take((size_t)BB * PRE * 4);
  float* topBox  = (float*)take((size_t)BB * PRE * 7 * 4);
  float* topS    = (float*)take((size_t)BB * PRE * 4);
  int*   topL    = (int*)  take((size_t)BB * PRE * 4);

  nms_all_kernel<<<BB, 1024, 0, stream>>>(boxes, cls, keys, labels, sel, mid,
                                          Pg, ARg, topBox, topS, topL, out);
}